// Round 6
// baseline (115.706 us; speedup 1.0000x reference)
//
#include <hip/hip_runtime.h>

#define MARGIN 0.3f
#define EPS 1e-6f

constexpr int B = 64, N = 512, D = 512;
constexpr int NIDS = 32;          // track ids in [-1, 32)

constexpr int MB_THREADS = 256;
constexpr int MB_WAVES = MB_THREADS / 64;            // 4
constexpr int ANCH_PER_WAVE = 4;                     // one fully-prefetched chunk
constexpr int A_BLOCK = MB_WAVES * ANCH_PER_WAVE;    // 16 anchors per block
constexpr int MB_BLOCKS = (B * N) / A_BLOCK;         // 2048 (32 blocks per batch)

// ws layout: float psum[2048]; float pcnt[2048]  (16 KB)

__global__ __launch_bounds__(MB_THREADS) void tl_main(const float* __restrict__ feats,
                                                      const int* __restrict__ ids,
                                                      float* __restrict__ psum,
                                                      float* __restrict__ pcnt) {
    __shared__ int s_ids[N];
    __shared__ int s_first[NIDS], s_second[NIDS];
    __shared__ int s_j0, s_jdiff, s_vcnt;
    __shared__ float s_wsum[MB_WAVES];
    __shared__ int s_wcnt[MB_WAVES];

    const int t = threadIdx.x;
    const int lane = t & 63;
    const int wave = t >> 6;

    // XCD swizzle: XCD x (= blockIdx%8) owns logical blocks x*256..x*256+255,
    // i.e. 8 whole batches -> pos/neg gathers stay in the local L2.
    const int logical = ((blockIdx.x & 7) << 8) | (blockIdx.x >> 3);
    const int b = logical >> 5;                  // 32 blocks per batch
    const int seg = (logical & 31) * A_BLOCK;    // first anchor of this block
    const float* __restrict__ bf = feats + (size_t)b * N * D;

    // --- issue this wave's 4 anchor-row loads FIRST (addresses depend only on
    //     blockIdx) so the whole table-build prologue runs under their latency ---
    float4 A0[ANCH_PER_WAVE], A1[ANCH_PER_WAVE];
    #pragma unroll
    for (int k = 0; k < ANCH_PER_WAVE; ++k) {
        const int i = seg + wave * ANCH_PER_WAVE + k;
        const float4* fa = (const float4*)(bf + (size_t)i * D) + lane * 2;
        A0[k] = fa[0]; A1[k] = fa[1];
    }

    // ---- per-batch table build (32x redundant across blocks; measured-cheap) ----
    if (t < NIDS) { s_first[t] = N; s_second[t] = N; }
    if (t == 0) { s_j0 = N; s_jdiff = N; s_vcnt = 0; }
    __syncthreads();

    const int v1 = ids[b * N + t];               // 2 ids per thread (256*2 == N)
    const int v2 = ids[b * N + t + 256];
    s_ids[t] = v1;
    s_ids[t + 256] = v2;
    const unsigned long long m1 = __ballot(v1 >= 0);
    const unsigned long long m2 = __ballot(v2 >= 0);
    if (lane == 0) atomicAdd(&s_vcnt, __popcll(m1) + __popcll(m2));
    if (v1 >= 0) { atomicMin(&s_first[v1], t);       atomicMin(&s_j0, t); }
    if (v2 >= 0) { atomicMin(&s_first[v2], t + 256); atomicMin(&s_j0, t + 256); }
    __syncthreads();
    const int id0 = (s_j0 < N) ? s_ids[s_j0] : -2;
    if (v1 >= 0) {
        if (s_first[v1] != t) atomicMin(&s_second[v1], t);
        if (v1 != id0) atomicMin(&s_jdiff, t);
    }
    if (v2 >= 0) {
        if (s_first[v2] != t + 256) atomicMin(&s_second[v2], t + 256);
        if (v2 != id0) atomicMin(&s_jdiff, t + 256);
    }
    __syncthreads();

    const int vcnt = s_vcnt;
    const int j0c = min(s_j0, N - 1), jdc = min(s_jdiff, N - 1);

    // Register-cache the two negative-candidate rows of this batch.
    const float4* n0p = (const float4*)(bf + (size_t)j0c * D) + lane * 2;
    const float4* n1p = (const float4*)(bf + (size_t)jdc * D) + lane * 2;
    const float4 n0a = n0p[0], n0b = n0p[1];
    const float4 n1a = n1p[0], n1b = n1p[1];

    // Per-anchor descriptors from the LDS tables, then all pos loads at once.
    int pj[ANCH_PER_WAVE]; bool okk[ANCH_PER_WAVE]; bool useN0[ANCH_PER_WAVE];
    #pragma unroll
    for (int k = 0; k < ANCH_PER_WAVE; ++k) {
        const int i = seg + wave * ANCH_PER_WAVE + k;
        const int vi = s_ids[i];
        bool ok = (vi >= 0) && (vcnt >= 2);
        int posj = 0, negj = -1;
        if (ok) {
            // argmax of bool mask = first True
            posj = (s_first[vi] != i) ? s_first[vi] : s_second[vi];
            negj = (vi != id0) ? s_j0 : s_jdiff;
            ok = (posj < N) && (negj < N);
        }
        okk[k] = ok;
        pj[k] = ok ? posj : 0;
        useN0[k] = (negj == s_j0);
    }

    float4 P0[ANCH_PER_WAVE], P1[ANCH_PER_WAVE];
    #pragma unroll
    for (int k = 0; k < ANCH_PER_WAVE; ++k) {
        const float4* fp = (const float4*)(bf + (size_t)pj[k] * D) + lane * 2;
        P0[k] = fp[0]; P1[k] = fp[1];
    }

    float wsum = 0.0f;
    int wcnt = 0;
    #pragma unroll
    for (int k = 0; k < ANCH_PER_WAVE; ++k) {
        const float4 m0 = useN0[k] ? n0a : n1a;
        const float4 m1v = useN0[k] ? n0b : n1b;
        float sap = 0.0f, san = 0.0f, dd;
        dd = A0[k].x - P0[k].x + EPS; sap += dd * dd;
        dd = A0[k].y - P0[k].y + EPS; sap += dd * dd;
        dd = A0[k].z - P0[k].z + EPS; sap += dd * dd;
        dd = A0[k].w - P0[k].w + EPS; sap += dd * dd;
        dd = A1[k].x - P1[k].x + EPS; sap += dd * dd;
        dd = A1[k].y - P1[k].y + EPS; sap += dd * dd;
        dd = A1[k].z - P1[k].z + EPS; sap += dd * dd;
        dd = A1[k].w - P1[k].w + EPS; sap += dd * dd;
        dd = A0[k].x - m0.x + EPS; san += dd * dd;
        dd = A0[k].y - m0.y + EPS; san += dd * dd;
        dd = A0[k].z - m0.z + EPS; san += dd * dd;
        dd = A0[k].w - m0.w + EPS; san += dd * dd;
        dd = A1[k].x - m1v.x + EPS; san += dd * dd;
        dd = A1[k].y - m1v.y + EPS; san += dd * dd;
        dd = A1[k].z - m1v.z + EPS; san += dd * dd;
        dd = A1[k].w - m1v.w + EPS; san += dd * dd;

        #pragma unroll
        for (int off = 32; off >= 1; off >>= 1) {
            sap += __shfl_xor(sap, off);
            san += __shfl_xor(san, off);
        }
        const float per = fmaxf(sqrtf(sap) - sqrtf(san) + MARGIN, 0.0f);
        wsum += okk[k] ? per : 0.0f;
        wcnt += okk[k] ? 1 : 0;
    }

    if (lane == 0) { s_wsum[wave] = wsum; s_wcnt[wave] = wcnt; }
    __syncthreads();
    if (t == 0) {
        float s = 0.0f; int c = 0;
        #pragma unroll
        for (int w = 0; w < MB_WAVES; ++w) { s += s_wsum[w]; c += s_wcnt[w]; }
        psum[blockIdx.x] = s;
        pcnt[blockIdx.x] = (float)c;
    }
}

__global__ __launch_bounds__(256) void tl_finalize(const float* __restrict__ psum,
                                                   const float* __restrict__ pcnt,
                                                   float* __restrict__ out) {
    __shared__ float s_s[4], s_c[4];
    const int t = threadIdx.x;
    float s = 0.0f, c = 0.0f;
    for (int k = t; k < MB_BLOCKS; k += 256) { s += psum[k]; c += pcnt[k]; }
    #pragma unroll
    for (int off = 32; off >= 1; off >>= 1) {
        s += __shfl_xor(s, off);
        c += __shfl_xor(c, off);
    }
    if ((t & 63) == 0) { s_s[t >> 6] = s; s_c[t >> 6] = c; }
    __syncthreads();
    if (t == 0) {
        const float S = s_s[0] + s_s[1] + s_s[2] + s_s[3];
        const float C = s_c[0] + s_c[1] + s_c[2] + s_c[3];
        const float loss = (C > 0.0f) ? (S / C) : 0.0f;
        out[0] = loss;   // tracking_loss = triplet + id(=0)
        out[1] = loss;   // loss_triplet
        out[2] = 0.0f;   // loss_id
    }
}

extern "C" void kernel_launch(void* const* d_in, const int* in_sizes, int n_in,
                              void* d_out, int out_size, void* d_ws, size_t ws_size,
                              hipStream_t stream) {
    const float* feats = (const float*)d_in[0];  // (B,N,D) fp32
    const int* ids = (const int*)d_in[1];        // (B,N) int32
    float* out = (float*)d_out;                  // 3 fp32 scalars

    float* psum = (float*)d_ws;                  // 2048 floats
    float* pcnt = psum + MB_BLOCKS;              // 2048 floats

    tl_main<<<MB_BLOCKS, MB_THREADS, 0, stream>>>(feats, ids, psum, pcnt);
    tl_finalize<<<1, 256, 0, stream>>>(psum, pcnt, out);
}

// Round 7
// 109.173 us; speedup vs baseline: 1.0598x; 1.0598x over previous
//
#include <hip/hip_runtime.h>

#define MARGIN 0.3f
#define EPS 1e-6f

constexpr int B = 64, N = 512, D = 512;
constexpr int NIDS = 32;          // track ids in [-1, 32)

constexpr int MB_THREADS = 512;                      // 8 waves; also == N for table build
constexpr int MB_WAVES = MB_THREADS / 64;            // 8
constexpr int ANCH_PER_WAVE = 8;                     // A hoisted; P in 2 chunks of 4
constexpr int A_BLOCK = MB_WAVES * ANCH_PER_WAVE;    // 64 anchors per block
constexpr int MB_BLOCKS = (B * N) / A_BLOCK;         // 512 (8 blocks per batch)

// ws layout: float psum[512]; float pcnt[512]  (4 KB)

__global__ __launch_bounds__(MB_THREADS) void tl_main(const float* __restrict__ feats,
                                                      const int* __restrict__ ids,
                                                      float* __restrict__ psum,
                                                      float* __restrict__ pcnt) {
    __shared__ int s_ids[N];
    __shared__ int s_first[NIDS], s_second[NIDS];
    __shared__ int s_j0, s_jdiff, s_vcnt;
    __shared__ float s_wsum[MB_WAVES];
    __shared__ int s_wcnt[MB_WAVES];

    const int t = threadIdx.x;
    const int lane = t & 63;
    const int wave = t >> 6;

    // XCD swizzle: XCD x (= blockIdx%8) owns logical blocks x*64..x*64+63,
    // i.e. 8 whole batches -> pos/neg gathers stay in the local L2's hot set.
    const int logical = ((blockIdx.x & 7) << 6) | (blockIdx.x >> 3);
    const int b = logical >> 3;                  // 8 blocks per batch
    const int seg = (logical & 7) * A_BLOCK;     // first anchor of this block
    const float* __restrict__ bf = feats + (size_t)b * N * D;

    // --- HOIST: issue this wave's 8 anchor-row loads FIRST (addresses depend
    //     only on blockIdx) so the serial table-build prologue runs under
    //     their latency. 64 VGPRs of payload. ---
    float4 A0[ANCH_PER_WAVE], A1[ANCH_PER_WAVE];
    #pragma unroll
    for (int k = 0; k < ANCH_PER_WAVE; ++k) {
        const int i = seg + wave * ANCH_PER_WAVE + k;
        const float4* fa = (const float4*)(bf + (size_t)i * D) + lane * 2;
        A0[k] = fa[0]; A1[k] = fa[1];
    }

    // ---- per-batch table build (8x redundant across blocks) ----
    if (t < NIDS) { s_first[t] = N; s_second[t] = N; }
    if (t == 0) { s_j0 = N; s_jdiff = N; s_vcnt = 0; }
    __syncthreads();

    const int v = ids[b * N + t];                // one id per thread (MB_THREADS == N)
    s_ids[t] = v;
    const unsigned long long m = __ballot(v >= 0);
    if (lane == 0) atomicAdd(&s_vcnt, __popcll(m));
    if (v >= 0) {
        atomicMin(&s_first[v], t);
        atomicMin(&s_j0, t);
    }
    __syncthreads();
    const int id0 = (s_j0 < N) ? s_ids[s_j0] : -2;
    if (v >= 0) {
        if (s_first[v] != t) atomicMin(&s_second[v], t);  // second occurrence
        if (v != id0) atomicMin(&s_jdiff, t);             // first valid w/ id != id0
    }
    __syncthreads();

    const int vcnt = s_vcnt;
    const int j0 = min(s_j0, N - 1), jdiff = min(s_jdiff, N - 1);

    // Register-cache the two negative-candidate rows of this batch.
    const float4* n0p = (const float4*)(bf + (size_t)j0 * D) + lane * 2;
    const float4* n1p = (const float4*)(bf + (size_t)jdiff * D) + lane * 2;
    const float4 n0a = n0p[0], n0b = n0p[1];
    const float4 n1a = n1p[0], n1b = n1p[1];

    float wsum = 0.0f;
    int wcnt = 0;

    #pragma unroll
    for (int c = 0; c < ANCH_PER_WAVE / 4; ++c) {
        const int base = seg + wave * ANCH_PER_WAVE + c * 4;
        const int ar = c * 4;                    // index into A0/A1

        int pj[4]; bool okk[4]; bool useN0[4];
        #pragma unroll
        for (int k = 0; k < 4; ++k) {
            const int i = base + k;
            const int vi = s_ids[i];
            bool ok = (vi >= 0) && (vcnt >= 2);
            int posj = 0, negj = 0;
            if (ok) {
                // argmax of bool mask = first True
                posj = (s_first[vi] != i) ? s_first[vi] : s_second[vi];
                negj = (vi != id0) ? s_j0 : s_jdiff;
                ok = (posj < N) && (negj < N);
            }
            okk[k] = ok;
            pj[k] = ok ? posj : 0;
            useN0[k] = (negj == s_j0);
        }

        // Issue all 8 independent pos loads before any compute.
        float4 P0[4], P1[4];
        #pragma unroll
        for (int k = 0; k < 4; ++k) {
            const float4* fp = (const float4*)(bf + (size_t)pj[k] * D) + lane * 2;
            P0[k] = fp[0]; P1[k] = fp[1];
        }

        #pragma unroll
        for (int k = 0; k < 4; ++k) {
            const float4 m0 = useN0[k] ? n0a : n1a;
            const float4 m1 = useN0[k] ? n0b : n1b;
            float sap = 0.0f, san = 0.0f, dd;
            dd = A0[ar + k].x - P0[k].x + EPS; sap += dd * dd;
            dd = A0[ar + k].y - P0[k].y + EPS; sap += dd * dd;
            dd = A0[ar + k].z - P0[k].z + EPS; sap += dd * dd;
            dd = A0[ar + k].w - P0[k].w + EPS; sap += dd * dd;
            dd = A1[ar + k].x - P1[k].x + EPS; sap += dd * dd;
            dd = A1[ar + k].y - P1[k].y + EPS; sap += dd * dd;
            dd = A1[ar + k].z - P1[k].z + EPS; sap += dd * dd;
            dd = A1[ar + k].w - P1[k].w + EPS; sap += dd * dd;
            dd = A0[ar + k].x - m0.x + EPS; san += dd * dd;
            dd = A0[ar + k].y - m0.y + EPS; san += dd * dd;
            dd = A0[ar + k].z - m0.z + EPS; san += dd * dd;
            dd = A0[ar + k].w - m0.w + EPS; san += dd * dd;
            dd = A1[ar + k].x - m1.x + EPS; san += dd * dd;
            dd = A1[ar + k].y - m1.y + EPS; san += dd * dd;
            dd = A1[ar + k].z - m1.z + EPS; san += dd * dd;
            dd = A1[ar + k].w - m1.w + EPS; san += dd * dd;

            #pragma unroll
            for (int off = 32; off >= 1; off >>= 1) {
                sap += __shfl_xor(sap, off);
                san += __shfl_xor(san, off);
            }
            const float per = fmaxf(sqrtf(sap) - sqrtf(san) + MARGIN, 0.0f);
            wsum += okk[k] ? per : 0.0f;
            wcnt += okk[k] ? 1 : 0;
        }
    }

    if (lane == 0) { s_wsum[wave] = wsum; s_wcnt[wave] = wcnt; }
    __syncthreads();
    if (t == 0) {
        float s = 0.0f; int c = 0;
        #pragma unroll
        for (int w = 0; w < MB_WAVES; ++w) { s += s_wsum[w]; c += s_wcnt[w]; }
        psum[blockIdx.x] = s;
        pcnt[blockIdx.x] = (float)c;
    }
}

__global__ __launch_bounds__(256) void tl_finalize(const float* __restrict__ psum,
                                                   const float* __restrict__ pcnt,
                                                   float* __restrict__ out) {
    __shared__ float s_s[4], s_c[4];
    const int t = threadIdx.x;
    float s = 0.0f, c = 0.0f;
    for (int k = t; k < MB_BLOCKS; k += 256) { s += psum[k]; c += pcnt[k]; }
    #pragma unroll
    for (int off = 32; off >= 1; off >>= 1) {
        s += __shfl_xor(s, off);
        c += __shfl_xor(c, off);
    }
    if ((t & 63) == 0) { s_s[t >> 6] = s; s_c[t >> 6] = c; }
    __syncthreads();
    if (t == 0) {
        const float S = s_s[0] + s_s[1] + s_s[2] + s_s[3];
        const float C = s_c[0] + s_c[1] + s_c[2] + s_c[3];
        const float loss = (C > 0.0f) ? (S / C) : 0.0f;
        out[0] = loss;   // tracking_loss = triplet + id(=0)
        out[1] = loss;   // loss_triplet
        out[2] = 0.0f;   // loss_id
    }
}

extern "C" void kernel_launch(void* const* d_in, const int* in_sizes, int n_in,
                              void* d_out, int out_size, void* d_ws, size_t ws_size,
                              hipStream_t stream) {
    const float* feats = (const float*)d_in[0];  // (B,N,D) fp32
    const int* ids = (const int*)d_in[1];        // (B,N) int32
    float* out = (float*)d_out;                  // 3 fp32 scalars

    float* psum = (float*)d_ws;                  // 512 floats
    float* pcnt = psum + MB_BLOCKS;              // 512 floats

    tl_main<<<MB_BLOCKS, MB_THREADS, 0, stream>>>(feats, ids, psum, pcnt);
    tl_finalize<<<1, 256, 0, stream>>>(psum, pcnt, out);
}

// Round 8
// 102.432 us; speedup vs baseline: 1.1296x; 1.0658x over previous
//
#include <hip/hip_runtime.h>

#define MARGIN 0.3f
#define EPS 1e-6f

constexpr int B = 64, N = 512, D = 512;
constexpr int NIDS = 32;          // track ids in [-1, 32)
constexpr int TAB = 68;           // first[32], second[32], j0, jdiff, vcnt, id0

constexpr int MB_THREADS = 256;
constexpr int MB_WAVES = MB_THREADS / 64;            // 4
constexpr int ANCH_PER_WAVE = 8;                     // 2 chunks of 4, prefetched
constexpr int A_BLOCK = MB_WAVES * ANCH_PER_WAVE;    // 32 anchors per block
constexpr int MB_BLOCKS = (B * N) / A_BLOCK;         // 1024 (16 blocks per batch)

// ws layout: int tabs[64*68] (17.4 KB); float psum[1024]; float pcnt[1024]

__global__ __launch_bounds__(512) void tl_tables(const int* __restrict__ ids,
                                                 int* __restrict__ tabs) {
    __shared__ int s_ids[N];
    __shared__ int s_first[NIDS], s_second[NIDS];
    __shared__ int s_j0, s_jdiff, s_vcnt;
    const int t = threadIdx.x;
    const int b = blockIdx.x;

    if (t < NIDS) { s_first[t] = N; s_second[t] = N; }
    if (t == 0) { s_j0 = N; s_jdiff = N; s_vcnt = 0; }
    __syncthreads();

    const int v = ids[b * N + t];          // one id per thread (512 == N)
    s_ids[t] = v;
    const unsigned long long m = __ballot(v >= 0);
    if ((t & 63) == 0) atomicAdd(&s_vcnt, __popcll(m));
    if (v >= 0) {
        atomicMin(&s_first[v], t);
        atomicMin(&s_j0, t);
    }
    __syncthreads();
    const int id0 = (s_j0 < N) ? s_ids[s_j0] : -2;
    if (v >= 0) {
        if (s_first[v] != t) atomicMin(&s_second[v], t);  // second occurrence
        if (v != id0) atomicMin(&s_jdiff, t);             // first valid w/ id != id0
    }
    __syncthreads();

    int* tb = tabs + b * TAB;
    if (t < NIDS)            tb[t] = s_first[t];
    else if (t < 2 * NIDS)   tb[t] = s_second[t - NIDS];
    else if (t == 64)        tb[64] = s_j0;
    else if (t == 65)        tb[65] = s_jdiff;
    else if (t == 66)        tb[66] = s_vcnt;
    else if (t == 67)        tb[67] = id0;
}

__global__ __launch_bounds__(MB_THREADS) void tl_main(const float* __restrict__ feats,
                                                      const int* __restrict__ ids,
                                                      const int* __restrict__ tabs,
                                                      float* __restrict__ psum,
                                                      float* __restrict__ pcnt) {
    __shared__ int s_tab[TAB];
    __shared__ int s_aids[A_BLOCK];
    __shared__ float s_wsum[MB_WAVES];
    __shared__ int s_wcnt[MB_WAVES];

    const int t = threadIdx.x;
    const int lane = t & 63;
    const int wave = t >> 6;

    // XCD swizzle: XCD x (= blockIdx%8) owns logical blocks x*128..x*128+127,
    // i.e. 8 whole batches -> gathers stay in the local L2.
    const int logical = ((blockIdx.x & 7) << 7) | (blockIdx.x >> 3);
    const int b = logical >> 4;                  // 16 blocks per batch
    const int seg = (logical & 15) * A_BLOCK;    // first anchor of this block
    const float* __restrict__ bf = feats + (size_t)b * N * D;

    // Tiny prologue: one 272 B table fill + 32 anchor ids, one barrier.
    if (t < TAB) s_tab[t] = tabs[b * TAB + t];
    if (t < A_BLOCK) s_aids[t] = ids[b * N + seg + t];
    __syncthreads();

    const int j0 = s_tab[64], jdiff = s_tab[65], vcnt = s_tab[66], id0 = s_tab[67];
    const int j0c = min(j0, N - 1), jdc = min(jdiff, N - 1);

    // Register-cache the two negative-candidate rows of this batch.
    const float4* n0p = (const float4*)(bf + (size_t)j0c * D) + lane * 2;
    const float4* n1p = (const float4*)(bf + (size_t)jdc * D) + lane * 2;
    const float4 n0a = n0p[0], n0b = n0p[1];
    const float4 n1a = n1p[0], n1b = n1p[1];

    float wsum = 0.0f;
    int wcnt = 0;

    #pragma unroll
    for (int c = 0; c < ANCH_PER_WAVE / 4; ++c) {
        const int lbase = wave * ANCH_PER_WAVE + c * 4;   // local anchor index

        int pj[4]; bool okk[4]; bool useN0[4];
        #pragma unroll
        for (int k = 0; k < 4; ++k) {
            const int li = lbase + k;
            const int i = seg + li;
            const int vi = s_aids[li];
            bool ok = (vi >= 0) && (vcnt >= 2);
            int posj = 0, negj = 0;
            if (ok) {
                // argmax of bool mask = first True
                const int f = s_tab[vi];
                posj = (f != i) ? f : s_tab[NIDS + vi];
                negj = (vi != id0) ? j0 : jdiff;
                ok = (posj < N) && (negj < N);
            }
            okk[k] = ok;
            pj[k] = ok ? posj : 0;
            useN0[k] = (negj == j0);
        }

        // Issue all 16 independent 16B loads before any compute.
        float4 A0[4], A1[4], P0[4], P1[4];
        #pragma unroll
        for (int k = 0; k < 4; ++k) {
            const int i = seg + lbase + k;
            const float4* fa = (const float4*)(bf + (size_t)i * D) + lane * 2;
            const float4* fp = (const float4*)(bf + (size_t)pj[k] * D) + lane * 2;
            A0[k] = fa[0]; A1[k] = fa[1];
            P0[k] = fp[0]; P1[k] = fp[1];
        }

        #pragma unroll
        for (int k = 0; k < 4; ++k) {
            const float4 m0 = useN0[k] ? n0a : n1a;
            const float4 m1 = useN0[k] ? n0b : n1b;
            float sap = 0.0f, san = 0.0f, dd;
            dd = A0[k].x - P0[k].x + EPS; sap += dd * dd;
            dd = A0[k].y - P0[k].y + EPS; sap += dd * dd;
            dd = A0[k].z - P0[k].z + EPS; sap += dd * dd;
            dd = A0[k].w - P0[k].w + EPS; sap += dd * dd;
            dd = A1[k].x - P1[k].x + EPS; sap += dd * dd;
            dd = A1[k].y - P1[k].y + EPS; sap += dd * dd;
            dd = A1[k].z - P1[k].z + EPS; sap += dd * dd;
            dd = A1[k].w - P1[k].w + EPS; sap += dd * dd;
            dd = A0[k].x - m0.x + EPS; san += dd * dd;
            dd = A0[k].y - m0.y + EPS; san += dd * dd;
            dd = A0[k].z - m0.z + EPS; san += dd * dd;
            dd = A0[k].w - m0.w + EPS; san += dd * dd;
            dd = A1[k].x - m1.x + EPS; san += dd * dd;
            dd = A1[k].y - m1.y + EPS; san += dd * dd;
            dd = A1[k].z - m1.z + EPS; san += dd * dd;
            dd = A1[k].w - m1.w + EPS; san += dd * dd;

            #pragma unroll
            for (int off = 32; off >= 1; off >>= 1) {
                sap += __shfl_xor(sap, off);
                san += __shfl_xor(san, off);
            }
            const float per = fmaxf(sqrtf(sap) - sqrtf(san) + MARGIN, 0.0f);
            wsum += okk[k] ? per : 0.0f;
            wcnt += okk[k] ? 1 : 0;
        }
    }

    if (lane == 0) { s_wsum[wave] = wsum; s_wcnt[wave] = wcnt; }
    __syncthreads();
    if (t == 0) {
        float s = 0.0f; int c = 0;
        #pragma unroll
        for (int w = 0; w < MB_WAVES; ++w) { s += s_wsum[w]; c += s_wcnt[w]; }
        psum[blockIdx.x] = s;
        pcnt[blockIdx.x] = (float)c;
    }
}

__global__ __launch_bounds__(256) void tl_finalize(const float* __restrict__ psum,
                                                   const float* __restrict__ pcnt,
                                                   float* __restrict__ out) {
    __shared__ float s_s[4], s_c[4];
    const int t = threadIdx.x;
    float s = 0.0f, c = 0.0f;
    for (int k = t; k < MB_BLOCKS; k += 256) { s += psum[k]; c += pcnt[k]; }
    #pragma unroll
    for (int off = 32; off >= 1; off >>= 1) {
        s += __shfl_xor(s, off);
        c += __shfl_xor(c, off);
    }
    if ((t & 63) == 0) { s_s[t >> 6] = s; s_c[t >> 6] = c; }
    __syncthreads();
    if (t == 0) {
        const float S = s_s[0] + s_s[1] + s_s[2] + s_s[3];
        const float C = s_c[0] + s_c[1] + s_c[2] + s_c[3];
        const float loss = (C > 0.0f) ? (S / C) : 0.0f;
        out[0] = loss;   // tracking_loss = triplet + id(=0)
        out[1] = loss;   // loss_triplet
        out[2] = 0.0f;   // loss_id
    }
}

extern "C" void kernel_launch(void* const* d_in, const int* in_sizes, int n_in,
                              void* d_out, int out_size, void* d_ws, size_t ws_size,
                              hipStream_t stream) {
    const float* feats = (const float*)d_in[0];  // (B,N,D) fp32
    const int* ids = (const int*)d_in[1];        // (B,N) int32
    float* out = (float*)d_out;                  // 3 fp32 scalars

    char* ws = (char*)d_ws;
    int* tabs = (int*)ws;                                   // 64*68 ints
    float* psum = (float*)(ws + sizeof(int) * B * TAB);     // 1024 floats
    float* pcnt = psum + MB_BLOCKS;                         // 1024 floats

    tl_tables<<<B, 512, 0, stream>>>(ids, tabs);
    tl_main<<<MB_BLOCKS, MB_THREADS, 0, stream>>>(feats, ids, tabs, psum, pcnt);
    tl_finalize<<<1, 256, 0, stream>>>(psum, pcnt, out);
}